// Round 1
// baseline (919.273 us; speedup 1.0000x reference)
//
#include <hip/hip_runtime.h>
#include <cstdint>

// ============================================================================
// QunatEncoderBlock: windowed attention block with int8 fake-quant.
// All qlinear / QK^T / PV matmuls are EXACT in int8xint8->int32 (MFMA i8),
// since fake_quant produces values  q*s  with q an int in [-128,127].
// ============================================================================

typedef int v4i __attribute__((ext_vector_type(4)));
typedef int8_t i8;

__device__ __forceinline__ i8 quant_i8(float x, float s) {
  float q = rintf(x / s);                  // round-half-even == jnp.round
  q = fminf(127.f, fmaxf(-128.f, q));
  return (i8)(int)q;
}

// ---------------------------------------------------------------------------
// weight fake-quant -> int8
// ---------------------------------------------------------------------------
__global__ __launch_bounds__(256) void k_wquant(const float* __restrict__ w,
                                                i8* __restrict__ o, int n,
                                                const float* __restrict__ wsc, int sidx) {
  int i = blockIdx.x * 256 + threadIdx.x;
  if (i < n) o[i] = quant_i8(w[i], wsc[sidx]);
}

// ---------------------------------------------------------------------------
// LN1 + window partition (pad 64->70, 5x5 windows of 14x14) + act quant a_s[4]
// one block per window token (19600 blocks); padded tokens -> 0
// ---------------------------------------------------------------------------
__global__ __launch_bounds__(256) void k_ln1(const float* __restrict__ x,
    const float* __restrict__ w, const float* __restrict__ b,
    const float* __restrict__ as, i8* __restrict__ outq) {
  int wt = blockIdx.x;                       // 0..19599
  int win = wt / 196, tok = wt - win * 196;
  int bb = win / 25, wrem = win - bb * 25, wh = wrem / 5, ww = wrem - wh * 5;
  int r = tok / 14, c = tok - r * 14;
  int y = wh * 14 + r, xx = ww * 14 + c;
  int tid = threadIdx.x;
  if (y >= 64 || xx >= 64) {                 // padded token: h = 0 -> q = 0
    i8* orow = outq + (size_t)wt * 768;
    orow[tid] = 0; orow[tid + 256] = 0; orow[tid + 512] = 0;
    return;
  }
  const float* row = x + (((size_t)bb * 64 + y) * 64 + xx) * 768;
  float v0 = row[tid], v1 = row[tid + 256], v2 = row[tid + 512];
  float s = v0 + v1 + v2, ss = v0 * v0 + v1 * v1 + v2 * v2;
  for (int off = 32; off > 0; off >>= 1) { s += __shfl_xor(s, off); ss += __shfl_xor(ss, off); }
  __shared__ float red[8];
  int wv = tid >> 6;
  if ((tid & 63) == 0) { red[wv] = s; red[4 + wv] = ss; }
  __syncthreads();
  s = red[0] + red[1] + red[2] + red[3];
  ss = red[4] + red[5] + red[6] + red[7];
  float mu = s * (1.0f / 768.0f);
  float var = ss * (1.0f / 768.0f) - mu * mu;
  float rstd = 1.0f / sqrtf(var + 1e-6f);
  float sq = as[4];
  i8* orow = outq + (size_t)wt * 768;
  orow[tid]       = quant_i8((v0 - mu) * rstd * w[tid]       + b[tid],       sq);
  orow[tid + 256] = quant_i8((v1 - mu) * rstd * w[tid + 256] + b[tid + 256], sq);
  orow[tid + 512] = quant_i8((v2 - mu) * rstd * w[tid + 512] + b[tid + 512], sq);
}

// ---------------------------------------------------------------------------
// LN2 + act quant a_s[6]; one block per token (16384 blocks); x2 lives in d_out
// ---------------------------------------------------------------------------
__global__ __launch_bounds__(256) void k_ln2(const float* __restrict__ x2,
    const float* __restrict__ w, const float* __restrict__ b,
    const float* __restrict__ as, i8* __restrict__ outq) {
  int tokg = blockIdx.x;
  int tid = threadIdx.x;
  const float* row = x2 + (size_t)tokg * 768;
  float v0 = row[tid], v1 = row[tid + 256], v2 = row[tid + 512];
  float s = v0 + v1 + v2, ss = v0 * v0 + v1 * v1 + v2 * v2;
  for (int off = 32; off > 0; off >>= 1) { s += __shfl_xor(s, off); ss += __shfl_xor(ss, off); }
  __shared__ float red[8];
  int wv = tid >> 6;
  if ((tid & 63) == 0) { red[wv] = s; red[4 + wv] = ss; }
  __syncthreads();
  s = red[0] + red[1] + red[2] + red[3];
  ss = red[4] + red[5] + red[6] + red[7];
  float mu = s * (1.0f / 768.0f);
  float var = ss * (1.0f / 768.0f) - mu * mu;
  float rstd = 1.0f / sqrtf(var + 1e-6f);
  float sq = as[6];
  i8* orow = outq + (size_t)tokg * 768;
  orow[tid]       = quant_i8((v0 - mu) * rstd * w[tid]       + b[tid],       sq);
  orow[tid + 256] = quant_i8((v1 - mu) * rstd * w[tid + 256] + b[tid + 256], sq);
  orow[tid + 512] = quant_i8((v2 - mu) * rstd * w[tid + 512] + b[tid + 512], sq);
}

// ---------------------------------------------------------------------------
// int8 GEMM: C[M,N] = A[M,K] x B[N,K]^T, 128x128 tile, BK=64,
// 4 waves 2x2, mfma_i32_16x16x64_i8, templated fused epilogue.
// N must be a multiple of 128; K a multiple of 64; M ragged-guarded.
// ---------------------------------------------------------------------------
template <class Epi>
__global__ __launch_bounds__(256) void k_gemm(const i8* __restrict__ A, const i8* __restrict__ B,
                                              int M, int N, int K, Epi epi) {
  __shared__ __align__(16) i8 As[128 * 64];
  __shared__ __align__(16) i8 Bs[128 * 64];
  const int tid = threadIdx.x;
  const int lane = tid & 63, wave = tid >> 6;
  const int quad = lane >> 4, lc = lane & 15;
  const int wr = wave >> 1, wc = wave & 1;
  const long bm = (long)blockIdx.y * 128, bn = (long)blockIdx.x * 128;
  const v4i vz = {0, 0, 0, 0};
  v4i acc[4][4];
#pragma unroll
  for (int i = 0; i < 4; i++)
#pragma unroll
    for (int j = 0; j < 4; j++) acc[i][j] = vz;

  const int r0 = tid >> 2, c0 = tid & 3;     // staging: row r0 (+64), 16B chunk c0
  for (int kt = 0; kt < K; kt += 64) {
    v4i a0 = (bm + r0 < M)      ? *(const v4i*)(A + (bm + r0)      * (size_t)K + kt + c0 * 16) : vz;
    v4i a1 = (bm + r0 + 64 < M) ? *(const v4i*)(A + (bm + r0 + 64) * (size_t)K + kt + c0 * 16) : vz;
    v4i b0 = *(const v4i*)(B + (bn + r0)      * (size_t)K + kt + c0 * 16);
    v4i b1 = *(const v4i*)(B + (bn + r0 + 64) * (size_t)K + kt + c0 * 16);
    __syncthreads();
    *(v4i*)(As + r0 * 64 + c0 * 16) = a0;
    *(v4i*)(As + (r0 + 64) * 64 + c0 * 16) = a1;
    *(v4i*)(Bs + r0 * 64 + c0 * 16) = b0;
    *(v4i*)(Bs + (r0 + 64) * 64 + c0 * 16) = b1;
    __syncthreads();
    v4i af[4], bf[4];
#pragma unroll
    for (int i = 0; i < 4; i++) af[i] = *(const v4i*)(As + (wr * 64 + i * 16 + lc) * 64 + quad * 16);
#pragma unroll
    for (int j = 0; j < 4; j++) bf[j] = *(const v4i*)(Bs + (wc * 64 + j * 16 + lc) * 64 + quad * 16);
#pragma unroll
    for (int i = 0; i < 4; i++)
#pragma unroll
      for (int j = 0; j < 4; j++)
        acc[i][j] = __builtin_amdgcn_mfma_i32_16x16x64_i8(af[i], bf[j], acc[i][j], 0, 0, 0);
  }
  Epi e = epi;
  e.init();
#pragma unroll
  for (int i = 0; i < 4; i++) {
    int gm0 = (int)bm + wr * 64 + i * 16 + quad * 4;   // C/D: row=(lane>>4)*4+reg, col=lane&15
#pragma unroll
    for (int j = 0; j < 4; j++) {
      int gn = (int)bn + wc * 64 + j * 16 + lc;
#pragma unroll
      for (int r = 0; r < 4; r++) {
        int gm = gm0 + r;
        if (gm < M) e(acc[i][j][r], gm, gn);
      }
    }
  }
}

// -------- epilogues --------
struct EpiQKV {   // split into q,k (token-major) and v^T (channel-major, stride 208), quantized
  const float* as; const float* wsc; const float* bias;
  i8 *qq, *kq, *vt;
  float sab, sq, sk, sv;
  __device__ void init() { sab = as[4] * wsc[0]; sq = as[0]; sk = as[1]; sv = as[2]; }
  __device__ void operator()(int acc, int m, int n) {
    float val = (float)acc * sab + bias[n];
    int t = n / 768, rem = n - t * 768;
    int head = rem >> 6, ch = rem & 63;
    float s = (t == 0) ? sq : (t == 1 ? sk : sv);
    i8 qi = quant_i8(val, s);
    int win = m / 196, tok = m - win * 196;
    size_t bh = (size_t)win * 12 + head;
    if (t == 0)      qq[(bh * 196 + tok) * 64 + ch] = qi;
    else if (t == 1) kq[(bh * 196 + tok) * 64 + ch] = qi;
    else             vt[(bh * 64 + ch) * 208 + tok] = qi;
  }
};

struct EpiProj {  // window reverse + unpad + shortcut add -> x2 (in d_out)
  const float* as; const float* wsc; const float* bias; const float* x0; float* out;
  float sab;
  __device__ void init() { sab = as[5] * wsc[1]; }
  __device__ void operator()(int acc, int m, int n) {
    float val = (float)acc * sab + bias[n];
    int win = m / 196, tok = m - win * 196;
    int bb = win / 25, wrem = win - bb * 25, wh = wrem / 5, ww = wrem - wh * 5;
    int r = tok / 14, c = tok - r * 14;
    int y = wh * 14 + r, xx = ww * 14 + c;
    if (y < 64 && xx < 64) {
      size_t o = (((size_t)bb * 64 + y) * 64 + xx) * 768 + n;
      out[o] = val + x0[o];
    }
  }
};

struct EpiLin1 {  // bias + exact gelu + quant a_s[7]
  const float* as; const float* wsc; const float* bias; i8* outq;
  float sab, sg;
  __device__ void init() { sab = as[6] * wsc[2]; sg = as[7]; }
  __device__ void operator()(int acc, int m, int n) {
    float val = (float)acc * sab + bias[n];
    float g = 0.5f * val * (1.0f + erff(val * 0.70710678118654752f));
    outq[(size_t)m * 3072 + n] = quant_i8(g, sg);
  }
};

struct EpiLin2 {  // bias + residual add into d_out
  const float* as; const float* wsc; const float* bias; float* out;
  float sab;
  __device__ void init() { sab = as[7] * wsc[3]; }
  __device__ void operator()(int acc, int m, int n) {
    out[(size_t)m * 768 + n] += (float)acc * sab + bias[n];
  }
};

// ---------------------------------------------------------------------------
// attention: one block per (window,head) = 1200 blocks, 4 waves.
// QK^T and PV via i8 MFMA (int-exact); decomposed rel-pos bias precomputed
// into LDS; softmax with max-subtract; P quantized (a_s[3]) through per-wave
// LDS tile (stride 272); output quantized with a_s[5] for proj input.
// ---------------------------------------------------------------------------
__global__ __launch_bounds__(256) void k_attn(const i8* __restrict__ qq, const i8* __restrict__ kq,
    const i8* __restrict__ vt, const float* __restrict__ rph, const float* __restrict__ rpw,
    const float* __restrict__ as, i8* __restrict__ outq) {
  __shared__ __align__(16) i8 Ps[4 * 16 * 272];   // per-wave 16x272 P tile
  __shared__ float relh[196 * 14];
  __shared__ float relw[196 * 14];
  const int bh = blockIdx.x;
  const int win = bh / 12, head = bh - win * 12;
  const int tid = threadIdx.x;
  const int lane = tid & 63, wave = tid >> 6;
  const int quad = lane >> 4, lc = lane & 15;
  const float s0 = as[0], s1 = as[1], s2 = as[2], s3 = as[3], s5 = as[5];

  for (int i = tid * 4; i < 4 * 16 * 272; i += 1024) *(int*)(Ps + i) = 0;  // zero P (pad cols)

  if (tid < 196) {   // rel_h/rel_w: (196 x 14) each, computed from quantized q
    const int* qrow = (const int*)(qq + ((size_t)bh * 196 + tid) * 64);
    float qf[64];
#pragma unroll
    for (int d = 0; d < 16; d++) {
      int wv = qrow[d];
      qf[d * 4 + 0] = (float)(i8)(wv & 0xff);
      qf[d * 4 + 1] = (float)(i8)((wv >> 8) & 0xff);
      qf[d * 4 + 2] = (float)(i8)((wv >> 16) & 0xff);
      qf[d * 4 + 3] = (float)(wv >> 24);
    }
    int hh = tid / 14, wwi = tid - hh * 14;
    for (int k = 0; k < 14; k++) {
      const float* ph = rph + (hh - k + 13) * 64;
      const float* pw = rpw + (wwi - k + 13) * 64;
      float ah = 0.f, aw = 0.f;
#pragma unroll
      for (int c2 = 0; c2 < 64; c2++) { ah += qf[c2] * ph[c2]; aw += qf[c2] * pw[c2]; }
      relh[tid * 14 + k] = ah * s0;
      relw[tid * 14 + k] = aw * s0;
    }
  }
  __syncthreads();

  const float ssc = s0 * s1 * 0.125f;   // scale for integer QK^T
  const float os = s2 * s3;             // scale for integer PV
  i8* Pw = Ps + wave * 16 * 272;
  const v4i vz = {0, 0, 0, 0};

  for (int t = wave; t < 16; t += 4) {  // 13 row-tiles, lockstep rounds for barriers
    const bool active = (t < 13);
    if (active) {
      v4i aq = *(const v4i*)(qq + ((size_t)bh * 196 + t * 16 + lc) * 64 + quad * 16);
      v4i sacc[13];
#pragma unroll
      for (int f = 0; f < 13; f++) {
        v4i bk = *(const v4i*)(kq + ((size_t)bh * 196 + f * 16 + lc) * 64 + quad * 16);
        sacc[f] = __builtin_amdgcn_mfma_i32_16x16x64_i8(aq, bk, vz, 0, 0, 0);
      }
      int rowbase = t * 16 + quad * 4;
      for (int r = 0; r < 4; r++) {
        int row = rowbase + r;
        int rr = row < 196 ? row : 195;
        float L[13];
#pragma unroll
        for (int f = 0; f < 13; f++) {
          int col = f * 16 + lc;
          if (col < 196) {
            int kh = col / 14, kw = col - kh * 14;
            L[f] = (float)sacc[f][r] * ssc + relh[rr * 14 + kh] + relw[rr * 14 + kw];
          } else L[f] = -1e30f;
        }
        float mx = L[0];
#pragma unroll
        for (int f = 1; f < 13; f++) mx = fmaxf(mx, L[f]);
        for (int off = 1; off < 16; off <<= 1) mx = fmaxf(mx, __shfl_xor(mx, off));
        float sum = 0.f;
#pragma unroll
        for (int f = 0; f < 13; f++) {
          int col = f * 16 + lc;
          float e2 = (col < 196) ? expf(L[f] - mx) : 0.f;
          L[f] = e2; sum += e2;
        }
        for (int off = 1; off < 16; off <<= 1) sum += __shfl_xor(sum, off);
        float inv = 1.0f / sum;
#pragma unroll
        for (int f = 0; f < 13; f++)
          Pw[(quad * 4 + r) * 272 + f * 16 + lc] = quant_i8(L[f] * inv, s3);
      }
    }
    __syncthreads();
    if (active) {
      v4i oacc[4];
#pragma unroll
      for (int nt = 0; nt < 4; nt++) oacc[nt] = vz;
#pragma unroll
      for (int kc = 0; kc < 4; kc++) {
        v4i ap = *(const v4i*)(Pw + lc * 272 + kc * 64 + quad * 16);
#pragma unroll
        for (int nt = 0; nt < 4; nt++) {
          v4i bv = *(const v4i*)(vt + ((size_t)bh * 64 + nt * 16 + lc) * 208 + kc * 64 + quad * 16);
          oacc[nt] = __builtin_amdgcn_mfma_i32_16x16x64_i8(ap, bv, oacc[nt], 0, 0, 0);
        }
      }
#pragma unroll
      for (int nt = 0; nt < 4; nt++) {
        int ch = nt * 16 + lc;
#pragma unroll
        for (int r = 0; r < 4; r++) {
          int row = t * 16 + quad * 4 + r;
          if (row < 196) {
            float val = (float)oacc[nt][r] * os;
            outq[((size_t)win * 196 + row) * 768 + head * 64 + ch] = quant_i8(val, s5);
          }
        }
      }
    }
    __syncthreads();
  }
}

// ---------------------------------------------------------------------------
extern "C" void kernel_launch(void* const* d_in, const int* in_sizes, int n_in,
                              void* d_out, int out_size, void* d_ws, size_t ws_size,
                              hipStream_t stream) {
  const float* x     = (const float*)d_in[0];
  const float* ln1w  = (const float*)d_in[1];
  const float* ln1b  = (const float*)d_in[2];
  const float* ln2w  = (const float*)d_in[3];
  const float* ln2b  = (const float*)d_in[4];
  const float* qkvw  = (const float*)d_in[5];
  const float* qkvb  = (const float*)d_in[6];
  const float* projw = (const float*)d_in[7];
  const float* projb = (const float*)d_in[8];
  const float* lin1w = (const float*)d_in[9];
  const float* lin1b = (const float*)d_in[10];
  const float* lin2w = (const float*)d_in[11];
  const float* lin2b = (const float*)d_in[12];
  const float* rph   = (const float*)d_in[13];
  const float* rpw   = (const float*)d_in[14];
  const float* as    = (const float*)d_in[15];
  const float* wsc   = (const float*)d_in[16];
  float* out = (float*)d_out;

  // ws layout (total 72,462,336 B), regions reused across stages:
  char* ws = (char*)d_ws;
  i8* big   = (i8*)ws;                         // 50,331,648 B
  i8* qq    = big;                             // 15,052,800  (1200*196*64)
  i8* kq    = big + 15052800;                  // 15,052,800
  i8* vt    = big + 2 * 15052800;              // 15,974,400  (1200*64*208)
  i8* mlpq  = big;                             // 50,331,648  (16384*3072), after attn
  i8* creg  = (i8*)(ws + 50331648);            // 15,052,800
  i8* winq  = creg;                            // qkv input
  i8* attno = creg;                            // proj input (after qkv dead)
  i8* yq    = creg;                            // lin1 input (after proj dead)
  i8* wqb   = (i8*)(ws + 50331648 + 15052800); // 7,077,888
  i8* qkvwq  = wqb;
  i8* projwq = wqb + 1769472;
  i8* lin1wq = projwq + 589824;
  i8* lin2wq = lin1wq + 2359296;

  k_wquant<<<(1769472 + 255) / 256, 256, 0, stream>>>(qkvw,  qkvwq,  1769472, wsc, 0);
  k_wquant<<<( 589824 + 255) / 256, 256, 0, stream>>>(projw, projwq,  589824, wsc, 1);
  k_wquant<<<(2359296 + 255) / 256, 256, 0, stream>>>(lin1w, lin1wq, 2359296, wsc, 2);
  k_wquant<<<(2359296 + 255) / 256, 256, 0, stream>>>(lin2w, lin2wq, 2359296, wsc, 3);

  k_ln1<<<19600, 256, 0, stream>>>(x, ln1w, ln1b, as, winq);

  { EpiQKV e{as, wsc, qkvb, qq, kq, vt};
    k_gemm<EpiQKV><<<dim3(2304 / 128, (19600 + 127) / 128), 256, 0, stream>>>(
        winq, qkvwq, 19600, 2304, 768, e); }

  k_attn<<<1200, 256, 0, stream>>>(qq, kq, vt, rph, rpw, as, attno);

  { EpiProj e{as, wsc, projb, x, out};
    k_gemm<EpiProj><<<dim3(768 / 128, (19600 + 127) / 128), 256, 0, stream>>>(
        attno, projwq, 19600, 768, 768, e); }

  k_ln2<<<16384, 256, 0, stream>>>(out, ln2w, ln2b, as, yq);

  { EpiLin1 e{as, wsc, lin1b, mlpq};
    k_gemm<EpiLin1><<<dim3(3072 / 128, 16384 / 128), 256, 0, stream>>>(
        yq, lin1wq, 16384, 3072, 768, e); }

  { EpiLin2 e{as, wsc, lin2b, out};
    k_gemm<EpiLin2><<<dim3(768 / 128, 16384 / 128), 256, 0, stream>>>(
        mlpq, lin2wq, 16384, 768, 3072, e); }
}

// Round 2
// 597.058 us; speedup vs baseline: 1.5397x; 1.5397x over previous
//
#include <hip/hip_runtime.h>
#include <cstdint>

// ============================================================================
// QunatEncoderBlock: windowed attention block with int8 fake-quant.
// All qlinear / QK^T / PV matmuls are EXACT in int8xint8->int32 (MFMA i8).
// Rel-pos bias via bf16 MFMA with hi/lo split tables (error ~2^-18).
// ============================================================================

typedef int   v4i __attribute__((ext_vector_type(4)));
typedef float v4f __attribute__((ext_vector_type(4)));
typedef short v8s __attribute__((ext_vector_type(8)));
typedef int8_t i8;

__device__ __forceinline__ i8 satq(float x) {   // x already scale-divided
  float q = rintf(x);
  q = fminf(127.f, fmaxf(-128.f, q));
  return (i8)(int)q;
}

__device__ __forceinline__ void gload16(const i8* g, i8* l) {
  __builtin_amdgcn_global_load_lds((const __attribute__((address_space(1))) void*)g,
                                   (__attribute__((address_space(3))) void*)l, 16, 0, 0);
}

__device__ __forceinline__ int pack4(const i8* q) {
  return ((int)(unsigned char)q[0]) | ((int)(unsigned char)q[1] << 8) |
         ((int)(unsigned char)q[2] << 16) | ((int)(unsigned char)q[3] << 24);
}

// ---------------------------------------------------------------------------
// weight fake-quant -> int8, 16 elements/thread
// ---------------------------------------------------------------------------
__global__ __launch_bounds__(256) void k_wquant(const float* __restrict__ w,
                                                i8* __restrict__ o, int n16,
                                                const float* __restrict__ wsc, int sidx) {
  int i = blockIdx.x * 256 + threadIdx.x;
  if (i >= n16) return;
  float inv = 1.0f / wsc[sidx];
  const float4* src = (const float4*)w + (size_t)i * 4;
  i8 buf[16];
#pragma unroll
  for (int t = 0; t < 4; t++) {
    float4 f = src[t];
    buf[t*4+0] = satq(f.x * inv); buf[t*4+1] = satq(f.y * inv);
    buf[t*4+2] = satq(f.z * inv); buf[t*4+3] = satq(f.w * inv);
  }
  *(v4i*)(o + (size_t)i * 16) = *(v4i*)buf;
}

// ---------------------------------------------------------------------------
// pack rel-pos tables for bf16 MFMA B-operand, hi/lo split.
// chunk c = (tb*2+nt)*4 + ks*2 + p ; frag = TB[c*512 + lane*8 .. +8]
// B[n][k] = table[n*64+k] (n<27 else 0), n = nt*16+(lane&15), k = ks*32+(lane>>4)*8+j
// ---------------------------------------------------------------------------
__global__ __launch_bounds__(256) void k_relpack(const float* __restrict__ rph,
    const float* __restrict__ rpw, short* __restrict__ TB) {
  int g = blockIdx.x * 256 + threadIdx.x;
  if (g >= 1024) return;
  int lane = g & 63, c = g >> 6;
  int p = c & 1, ks = (c >> 1) & 1, nt = (c >> 2) & 1, tb = c >> 3;
  const float* src = tb ? rpw : rph;
  int n = nt * 16 + (lane & 15);
  int k0 = ks * 32 + (lane >> 4) * 8;
  short outv[8];
#pragma unroll
  for (int j = 0; j < 8; j++) {
    float v = (n < 27) ? src[n * 64 + k0 + j] : 0.f;
    unsigned u = __float_as_uint(v);
    unsigned hi = (u + 0x7fffu + ((u >> 16) & 1u)) >> 16;
    if (p == 0) outv[j] = (short)hi;
    else {
      float lof = v - __uint_as_float(hi << 16);
      unsigned ul = __float_as_uint(lof);
      outv[j] = (short)((ul + 0x7fffu + ((ul >> 16) & 1u)) >> 16);
    }
  }
  *(v8s*)(TB + (size_t)c * 512 + lane * 8) = *(v8s*)outv;
}

// ---------------------------------------------------------------------------
// LN1: wave per window-token (pad 64->70, 5x5 windows of 14x14), quant a_s[4]
// ---------------------------------------------------------------------------
__global__ __launch_bounds__(256) void k_ln1(const float* __restrict__ x,
    const float* __restrict__ w, const float* __restrict__ b,
    const float* __restrict__ as, i8* __restrict__ outq) {
  int wt = blockIdx.x * 4 + (threadIdx.x >> 6);
  int lane = threadIdx.x & 63;
  int win = wt / 196, tok = wt - win * 196;
  int bb = win / 25, wrem = win - bb * 25, wh = wrem / 5, ww = wrem - wh * 5;
  int r = tok / 14, c = tok - r * 14;
  int y = wh * 14 + r, xx = ww * 14 + c;
  i8* dst = outq + (size_t)wt * 768 + lane * 12;
  if (y >= 64 || xx >= 64) {
    ((int*)dst)[0] = 0; ((int*)dst)[1] = 0; ((int*)dst)[2] = 0;
    return;
  }
  const float* row = x + (((size_t)bb * 64 + y) * 64 + xx) * 768 + lane * 12;
  float v[12];
  *(float4*)(v)     = *(const float4*)(row);
  *(float4*)(v + 4) = *(const float4*)(row + 4);
  *(float4*)(v + 8) = *(const float4*)(row + 8);
  float s = 0.f, ss = 0.f;
#pragma unroll
  for (int j = 0; j < 12; j++) { s += v[j]; ss += v[j] * v[j]; }
#pragma unroll
  for (int off = 1; off < 64; off <<= 1) { s += __shfl_xor(s, off); ss += __shfl_xor(ss, off); }
  float mu = s * (1.0f / 768.0f);
  float var = ss * (1.0f / 768.0f) - mu * mu;
  float rstd = 1.0f / sqrtf(var + 1e-6f);
  float inv = 1.0f / as[4];
  float wv[12], bv[12];
  *(float4*)(wv)     = *(const float4*)(w + lane * 12);
  *(float4*)(wv + 4) = *(const float4*)(w + lane * 12 + 4);
  *(float4*)(wv + 8) = *(const float4*)(w + lane * 12 + 8);
  *(float4*)(bv)     = *(const float4*)(b + lane * 12);
  *(float4*)(bv + 4) = *(const float4*)(b + lane * 12 + 4);
  *(float4*)(bv + 8) = *(const float4*)(b + lane * 12 + 8);
  i8 q[12];
#pragma unroll
  for (int j = 0; j < 12; j++) q[j] = satq(((v[j] - mu) * rstd * wv[j] + bv[j]) * inv);
  ((int*)dst)[0] = pack4(q); ((int*)dst)[1] = pack4(q + 4); ((int*)dst)[2] = pack4(q + 8);
}

// ---------------------------------------------------------------------------
// LN2: wave per token, quant a_s[6]
// ---------------------------------------------------------------------------
__global__ __launch_bounds__(256) void k_ln2(const float* __restrict__ x2,
    const float* __restrict__ w, const float* __restrict__ b,
    const float* __restrict__ as, i8* __restrict__ outq) {
  int tokg = blockIdx.x * 4 + (threadIdx.x >> 6);
  int lane = threadIdx.x & 63;
  const float* row = x2 + (size_t)tokg * 768 + lane * 12;
  float v[12];
  *(float4*)(v)     = *(const float4*)(row);
  *(float4*)(v + 4) = *(const float4*)(row + 4);
  *(float4*)(v + 8) = *(const float4*)(row + 8);
  float s = 0.f, ss = 0.f;
#pragma unroll
  for (int j = 0; j < 12; j++) { s += v[j]; ss += v[j] * v[j]; }
#pragma unroll
  for (int off = 1; off < 64; off <<= 1) { s += __shfl_xor(s, off); ss += __shfl_xor(ss, off); }
  float mu = s * (1.0f / 768.0f);
  float var = ss * (1.0f / 768.0f) - mu * mu;
  float rstd = 1.0f / sqrtf(var + 1e-6f);
  float inv = 1.0f / as[6];
  float wv[12], bv[12];
  *(float4*)(wv)     = *(const float4*)(w + lane * 12);
  *(float4*)(wv + 4) = *(const float4*)(w + lane * 12 + 4);
  *(float4*)(wv + 8) = *(const float4*)(w + lane * 12 + 8);
  *(float4*)(bv)     = *(const float4*)(b + lane * 12);
  *(float4*)(bv + 4) = *(const float4*)(b + lane * 12 + 4);
  *(float4*)(bv + 8) = *(const float4*)(b + lane * 12 + 8);
  i8* dst = outq + (size_t)tokg * 768 + lane * 12;
  i8 q[12];
#pragma unroll
  for (int j = 0; j < 12; j++) q[j] = satq(((v[j] - mu) * rstd * wv[j] + bv[j]) * inv);
  ((int*)dst)[0] = pack4(q); ((int*)dst)[1] = pack4(q + 4); ((int*)dst)[2] = pack4(q + 8);
}

// ---------------------------------------------------------------------------
// int8 GEMM: C[M,N] = A[M,K] x B[N,K]^T, 128x128 tile, BK=64, m97 structure
// with global_load_lds width-16 staging. N%128==0, K%64==0, M%4==0.
// ---------------------------------------------------------------------------
template <class Epi>
__global__ __launch_bounds__(256) void k_gemm(const i8* __restrict__ A, const i8* __restrict__ B,
                                              int M, int N, int K, Epi epi) {
  __shared__ __align__(16) i8 As[128 * 64];
  __shared__ __align__(16) i8 Bs[128 * 64];
  const int tid = threadIdx.x;
  const int lane = tid & 63, wave = tid >> 6;
  const int quad = lane >> 4, lc = lane & 15;
  const int wr = wave >> 1, wc = wave & 1;
  const long bm = (long)blockIdx.y * 128, bn = (long)blockIdx.x * 128;
  const v4i vz = {0, 0, 0, 0};
  v4i acc[4][4];
#pragma unroll
  for (int i = 0; i < 4; i++)
#pragma unroll
    for (int j = 0; j < 4; j++) acc[i][j] = vz;

  const int r0 = tid >> 2, c0 = tid & 3;
  long rA0 = bm + r0;      if (rA0 >= M) rA0 = 0;
  long rA1 = bm + r0 + 64; if (rA1 >= M) rA1 = 0;
  const i8* pA0 = A + rA0 * (size_t)K + c0 * 16;
  const i8* pA1 = A + rA1 * (size_t)K + c0 * 16;
  const i8* pB0 = B + (bn + r0)      * (size_t)K + c0 * 16;
  const i8* pB1 = B + (bn + r0 + 64) * (size_t)K + c0 * 16;
  i8* lA0 = As + tid * 16;
  i8* lA1 = As + 4096 + tid * 16;
  i8* lB0 = Bs + tid * 16;
  i8* lB1 = Bs + 4096 + tid * 16;

  for (int kt = 0; kt < K; kt += 64) {
    __syncthreads();
    gload16(pA0, lA0); gload16(pA1, lA1);
    gload16(pB0, lB0); gload16(pB1, lB1);
    pA0 += 64; pA1 += 64; pB0 += 64; pB1 += 64;
    __syncthreads();
    v4i af[4], bf[4];
#pragma unroll
    for (int i = 0; i < 4; i++) af[i] = *(const v4i*)(As + (wr * 64 + i * 16 + lc) * 64 + quad * 16);
#pragma unroll
    for (int j = 0; j < 4; j++) bf[j] = *(const v4i*)(Bs + (wc * 64 + j * 16 + lc) * 64 + quad * 16);
#pragma unroll
    for (int i = 0; i < 4; i++)
#pragma unroll
      for (int j = 0; j < 4; j++)
        acc[i][j] = __builtin_amdgcn_mfma_i32_16x16x64_i8(af[i], bf[j], acc[i][j], 0, 0, 0);
  }
  Epi e = epi;
  e.init();
#pragma unroll
  for (int i = 0; i < 4; i++) {
    int gm0 = (int)bm + wr * 64 + i * 16 + quad * 4;   // C/D: row=quad*4+reg, col=lc
#pragma unroll
    for (int j = 0; j < 4; j++) {
      int gn = (int)bn + wc * 64 + j * 16 + lc;
      if (gm0 < M) e.store4(acc[i][j], gm0, gn);
    }
  }
}

// -------- epilogues (store4: 4 consecutive rows m0..m0+3, all < M) --------
struct EpiQKV {   // split into q,k (token-major) and v^T (ch-major, stride 256)
  const float* as; const float* wsc; const float* bias;
  i8 *qq, *kq, *vt;
  float sab, invq, invk, invv;
  __device__ void init() {
    sab = as[4] * wsc[0]; invq = 1.f / as[0]; invk = 1.f / as[1]; invv = 1.f / as[2];
  }
  __device__ void store4(const v4i a, int m0, int n) {
    int t = n / 768, rem = n - t * 768;
    int head = rem >> 6, ch = rem & 63;
    int win = m0 / 196, tok0 = m0 - win * 196;   // m0%4==0, 196%4==0: no window straddle
    size_t bh = (size_t)win * 12 + head;
    float bv = bias[n];
    if (t == 2) {
      i8 q[4];
#pragma unroll
      for (int r = 0; r < 4; r++) q[r] = satq(((float)a[r] * sab + bv) * invv);
      *(int*)(vt + (bh * 64 + ch) * 256 + tok0) = pack4(q);
    } else {
      float inv = (t == 0) ? invq : invk;
      i8* dst = (t == 0 ? qq : kq) + (bh * 196 + tok0) * 64 + ch;
#pragma unroll
      for (int r = 0; r < 4; r++) dst[(size_t)r * 64] = satq(((float)a[r] * sab + bv) * inv);
    }
  }
};

struct EpiProj {  // window reverse + unpad + shortcut add -> x2 (in d_out)
  const float* as; const float* wsc; const float* bias; const float* x0; float* out;
  float sab;
  __device__ void init() { sab = as[5] * wsc[1]; }
  __device__ void store4(const v4i a, int m0, int n) {
    int win = m0 / 196, tok0 = m0 - win * 196;
    int bb = win / 25, wrem = win - bb * 25, wh = wrem / 5, ww = wrem - wh * 5;
    float bv = bias[n];
#pragma unroll
    for (int r = 0; r < 4; r++) {
      int tok = tok0 + r;
      int rr = tok / 14, cc = tok - rr * 14;
      int y = wh * 14 + rr, xx = ww * 14 + cc;
      if (y < 64 && xx < 64) {
        size_t o = (((size_t)bb * 64 + y) * 64 + xx) * 768 + n;
        out[o] = (float)a[r] * sab + bv + x0[o];
      }
    }
  }
};

struct EpiLin1 {  // bias + exact gelu + quant a_s[7]
  const float* as; const float* wsc; const float* bias; i8* outq;
  float sab, invg;
  __device__ void init() { sab = as[6] * wsc[2]; invg = 1.f / as[7]; }
  __device__ void store4(const v4i a, int m0, int n) {
    float bv = bias[n];
#pragma unroll
    for (int r = 0; r < 4; r++) {
      float v = (float)a[r] * sab + bv;
      float g = 0.5f * v * (1.0f + erff(v * 0.70710678118654752f));
      outq[(size_t)(m0 + r) * 3072 + n] = satq(g * invg);
    }
  }
};

struct EpiLin2 {  // bias + residual add into d_out
  const float* as; const float* wsc; const float* bias; float* out;
  float sab;
  __device__ void init() { sab = as[7] * wsc[3]; }
  __device__ void store4(const v4i a, int m0, int n) {
    float bv = bias[n];
#pragma unroll
    for (int r = 0; r < 4; r++) {
      size_t o = (size_t)(m0 + r) * 768 + n;
      out[o] += (float)a[r] * sab + bv;
    }
  }
};

// ---------------------------------------------------------------------------
// attention: block = (win*12+head, half). Waves fully independent, NO barriers.
// Rel-pos bias via bf16 MFMA (hi/lo split tables). QK^T & PV via i8 MFMA.
// ---------------------------------------------------------------------------
__global__ __launch_bounds__(256) void k_attn(const i8* __restrict__ qq, const i8* __restrict__ kq,
    const i8* __restrict__ vt, const short* __restrict__ TB,
    const float* __restrict__ as, i8* __restrict__ outq) {
  __shared__ __align__(16) i8 Ps[4][16 * 272];    // per-wave P tile
  __shared__ float relS[4][16][64];               // per-wave rel bias [row][d(h)|32+d(w)]
  const int bh = blockIdx.x, half = blockIdx.y;
  const int win = bh / 12, head = bh - win * 12;
  const int tid = threadIdx.x;
  const int lane = tid & 63, wave = tid >> 6;
  const int quad = lane >> 4, lc = lane & 15;
  const float s0 = as[0];
  const float ssc = s0 * as[1] * 0.125f;
  const float invs3 = 1.0f / as[3];
  const float oscale = as[2] * as[3] / as[5];
  i8* Pw = Ps[wave];
  // zero own pad cols [192,256)
  for (int idx = lane; idx < 256; idx += 64)
    *(int*)(Pw + (idx >> 4) * 272 + 192 + (idx & 15) * 4) = 0;

  int ckh[13], ckw[13]; bool cok[13];
#pragma unroll
  for (int f = 0; f < 13; f++) {
    int col = f * 16 + lc;
    cok[f] = col < 196;
    ckh[f] = col / 14; ckw[f] = col - ckh[f] * 14;
  }

  const v8s* TBv = (const v8s*)TB;
  const v4i vz = {0, 0, 0, 0};
  const int base = half * 7, cnt = half ? 6 : 7;

  for (int r2 = 0; r2 < 2; r2++) {
    int ti = r2 * 4 + wave;
    if (ti >= cnt) break;
    int t = base + ti;

    // ---- rel-pos bias via bf16 MFMA ----
    {
      int arow = t * 16 + lc; if (arow > 195) arow = 195;
      const i8* qrow = qq + ((size_t)bh * 196 + arow) * 64;
      v8s af[2];
#pragma unroll
      for (int ks = 0; ks < 2; ks++) {
        const i8* p = qrow + ks * 32 + quad * 8;
#pragma unroll
        for (int j = 0; j < 8; j++)
          af[ks][j] = (short)(__float_as_uint((float)p[j]) >> 16);  // exact int->bf16
      }
      v4f rh0 = {0,0,0,0}, rh1 = {0,0,0,0}, rw0 = {0,0,0,0}, rw1 = {0,0,0,0};
#pragma unroll
      for (int ks = 0; ks < 2; ks++)
#pragma unroll
        for (int p2 = 0; p2 < 2; p2++) {
          rh0 = __builtin_amdgcn_mfma_f32_16x16x32_bf16(af[ks], TBv[(0*4 + ks*2 + p2)*64 + lane], rh0, 0, 0, 0);
          rh1 = __builtin_amdgcn_mfma_f32_16x16x32_bf16(af[ks], TBv[(1*4 + ks*2 + p2)*64 + lane], rh1, 0, 0, 0);
          rw0 = __builtin_amdgcn_mfma_f32_16x16x32_bf16(af[ks], TBv[(2*4 + ks*2 + p2)*64 + lane], rw0, 0, 0, 0);
          rw1 = __builtin_amdgcn_mfma_f32_16x16x32_bf16(af[ks], TBv[(3*4 + ks*2 + p2)*64 + lane], rw1, 0, 0, 0);
        }
#pragma unroll
      for (int r = 0; r < 4; r++) {
        int rl = quad * 4 + r;
        relS[wave][rl][lc]      = rh0[r] * s0;
        relS[wave][rl][16 + lc] = rh1[r] * s0;
        relS[wave][rl][32 + lc] = rw0[r] * s0;
        relS[wave][rl][48 + lc] = rw1[r] * s0;
      }
    }

    // ---- QK^T (int-exact) ----
    v4i aq = *(const v4i*)(qq + ((size_t)bh * 196 + t * 16 + lc) * 64 + quad * 16);
    v4i sacc[13];
#pragma unroll
    for (int f = 0; f < 13; f++) {
      v4i bk = *(const v4i*)(kq + ((size_t)bh * 196 + f * 16 + lc) * 64 + quad * 16);
      sacc[f] = __builtin_amdgcn_mfma_i32_16x16x64_i8(aq, bk, vz, 0, 0, 0);
    }

    // ---- softmax + P quant ----
#pragma unroll
    for (int r = 0; r < 4; r++) {
      int rl = quad * 4 + r;
      int row = t * 16 + rl;
      int qh = row / 14, qw = row - qh * 14;
      const float* rH = &relS[wave][rl][13 + qh];        // rH[-kh]
      const float* rW = &relS[wave][rl][32 + 13 + qw];   // rW[-kw]
      float L[13];
#pragma unroll
      for (int f = 0; f < 13; f++)
        L[f] = cok[f] ? fmaf((float)sacc[f][r], ssc, rH[-ckh[f]] + rW[-ckw[f]]) : -1e30f;
      float mx = L[0];
#pragma unroll
      for (int f = 1; f < 13; f++) mx = fmaxf(mx, L[f]);
#pragma unroll
      for (int off = 1; off < 16; off <<= 1) mx = fmaxf(mx, __shfl_xor(mx, off));
      float sum = 0.f;
#pragma unroll
      for (int f = 0; f < 13; f++) { float e = __expf(L[f] - mx); L[f] = e; sum += e; }
#pragma unroll
      for (int off = 1; off < 16; off <<= 1) sum += __shfl_xor(sum, off);
      float cq = (1.0f / sum) * invs3;
#pragma unroll
      for (int f = 0; f < 13; f++)
        Pw[rl * 272 + f * 16 + lc] = satq(L[f] * cq);
    }

    // ---- PV (int-exact) ----
    v4i oacc[4];
#pragma unroll
    for (int nt = 0; nt < 4; nt++) oacc[nt] = vz;
#pragma unroll
    for (int kc = 0; kc < 4; kc++) {
      v4i ap = *(const v4i*)(Pw + lc * 272 + kc * 64 + quad * 16);
#pragma unroll
      for (int nt = 0; nt < 4; nt++) {
        v4i bv = *(const v4i*)(vt + ((size_t)bh * 64 + nt * 16 + lc) * 256 + kc * 64 + quad * 16);
        oacc[nt] = __builtin_amdgcn_mfma_i32_16x16x64_i8(ap, bv, oacc[nt], 0, 0, 0);
      }
    }
#pragma unroll
    for (int nt = 0; nt < 4; nt++) {
      int ch = nt * 16 + lc;
#pragma unroll
      for (int r = 0; r < 4; r++) {
        int row = t * 16 + quad * 4 + r;
        if (row < 196)
          outq[((size_t)win * 196 + row) * 768 + head * 64 + ch] = satq((float)oacc[nt][r] * oscale);
      }
    }
  }
}

// ---------------------------------------------------------------------------
extern "C" void kernel_launch(void* const* d_in, const int* in_sizes, int n_in,
                              void* d_out, int out_size, void* d_ws, size_t ws_size,
                              hipStream_t stream) {
  const float* x     = (const float*)d_in[0];
  const float* ln1w  = (const float*)d_in[1];
  const float* ln1b  = (const float*)d_in[2];
  const float* ln2w  = (const float*)d_in[3];
  const float* ln2b  = (const float*)d_in[4];
  const float* qkvw  = (const float*)d_in[5];
  const float* qkvb  = (const float*)d_in[6];
  const float* projw = (const float*)d_in[7];
  const float* projb = (const float*)d_in[8];
  const float* lin1w = (const float*)d_in[9];
  const float* lin1b = (const float*)d_in[10];
  const float* lin2w = (const float*)d_in[11];
  const float* lin2b = (const float*)d_in[12];
  const float* rph   = (const float*)d_in[13];
  const float* rpw   = (const float*)d_in[14];
  const float* as    = (const float*)d_in[15];
  const float* wsc   = (const float*)d_in[16];
  float* out = (float*)d_out;

  // ws layout (72,462,336 B total), regions reused across stages:
  char* ws = (char*)d_ws;
  i8* big    = (i8*)ws;                          // 50,331,648
  i8* qq     = big;                              // 15,052,800 (1200*196*64)
  i8* kq     = big + 15052800;                   // 15,052,800
  i8* vt     = big + 30105600;                   // 19,660,800 (1200*64*256)
  short* TB  = (short*)(big + 49766400);         //     16,384 (rel tables; dead before lin1)
  i8* mlpq   = big;                              // 50,331,648 (16384*3072), after attn
  i8* creg   = (i8*)(ws + 50331648);             // 15,052,800
  i8* winq   = creg;                             // qkv input
  i8* attno  = creg;                             // proj input (after qkv dead)
  i8* yq     = creg;                             // lin1 input (after proj dead)
  i8* wqb    = (i8*)(ws + 65384448);             //  7,077,888
  i8* qkvwq  = wqb;
  i8* projwq = wqb + 1769472;
  i8* lin1wq = projwq + 589824;
  i8* lin2wq = lin1wq + 2359296;

  k_wquant<<<(110592 + 255) / 256, 256, 0, stream>>>(qkvw,  qkvwq,  110592, wsc, 0);
  k_wquant<<<( 36864 + 255) / 256, 256, 0, stream>>>(projw, projwq,  36864, wsc, 1);
  k_wquant<<<(147456 + 255) / 256, 256, 0, stream>>>(lin1w, lin1wq, 147456, wsc, 2);
  k_wquant<<<(147456 + 255) / 256, 256, 0, stream>>>(lin2w, lin2wq, 147456, wsc, 3);
  k_relpack<<<4, 256, 0, stream>>>(rph, rpw, TB);

  k_ln1<<<4900, 256, 0, stream>>>(x, ln1w, ln1b, as, winq);

  { EpiQKV e{as, wsc, qkvb, qq, kq, vt};
    k_gemm<EpiQKV><<<dim3(18, 154), 256, 0, stream>>>(winq, qkvwq, 19600, 2304, 768, e); }

  k_attn<<<dim3(1200, 2), 256, 0, stream>>>(qq, kq, vt, TB, as, attno);

  { EpiProj e{as, wsc, projb, x, out};
    k_gemm<EpiProj><<<dim3(6, 154), 256, 0, stream>>>(attno, projwq, 19600, 768, 768, e); }

  k_ln2<<<4096, 256, 0, stream>>>(out, ln2w, ln2b, as, yq);

  { EpiLin1 e{as, wsc, lin1b, mlpq};
    k_gemm<EpiLin1><<<dim3(24, 128), 256, 0, stream>>>(yq, lin1wq, 16384, 3072, 768, e); }

  { EpiLin2 e{as, wsc, lin2b, out};
    k_gemm<EpiLin2><<<dim3(6, 128), 256, 0, stream>>>(mlpq, lin2wq, 16384, 768, 3072, e); }
}